// Round 8
// baseline (337.400 us; speedup 1.0000x reference)
//
#include <hip/hip_runtime.h>
#include <math.h>

// Problem constants
#define T_TOKENS 32768
#define DIM      2048
#define NEXP     256
#define NGROUP   8
#define GSIZE    32
#define TOPG     4
#define TOPK     8
#define SCALE    2.5
#define TAU      2e-5f     // rescue margin; 3-term bf16-split err sigma ~4e-7

// Main-pass tiling
#define BM  64
#define NIT 32             // iterations of 64-k (2 sub-steps of 32)
#define SC_STRIDE 257
#define NCONS 512          // consumer threads (8 waves); producers: tid 512..639

#define RLIST_OFF 16                 // ints; ws[0] = counter
#define WPACK_OFF_BYTES (1 << 18)    // 256 KiB into d_ws

typedef __attribute__((ext_vector_type(8))) short bf16x8;
typedef __attribute__((ext_vector_type(8))) unsigned short u16x8;
typedef __attribute__((ext_vector_type(4))) float f32x4;

__device__ __forceinline__ unsigned short f2bf_rne(float f) {
    unsigned u = __float_as_uint(f);
    u += 0x7fffu + ((u >> 16) & 1u);
    return (unsigned short)(u >> 16);
}
__device__ __forceinline__ float bf2f(unsigned short h) {
    return __uint_as_float(((unsigned)h) << 16);
}

// ------------------------------------------------------------- pack W ----
// Wpack slot (s, n, h, lane) holds 8 bf16: W[e=16n+(lane&15)][k=32s+(lane>>4)*8+i]
__global__ void pack_w_kernel(const float* __restrict__ Wt,
                              unsigned short* __restrict__ wp,
                              int* __restrict__ ws) {
    if (blockIdx.x == 0 && threadIdx.x == 0) ws[0] = 0;   // rescue counter
    const int slot = blockIdx.x * 256 + threadIdx.x;      // 0..65535
    const int lane = slot & 63;
    const int n    = (slot >> 6) & 15;
    const int s    = slot >> 10;
    const int e    = n * 16 + (lane & 15);
    const int k0   = s * 32 + (lane >> 4) * 8;
    const float* src = Wt + (size_t)e * DIM + k0;
    const float4 v0 = *(const float4*)src;
    const float4 v1 = *(const float4*)(src + 4);
    const float a[8] = {v0.x, v0.y, v0.z, v0.w, v1.x, v1.y, v1.z, v1.w};
    union { unsigned short u[8]; u16x8 v; } uh, ul;
    #pragma unroll
    for (int i = 0; i < 8; ++i) {
        const unsigned short hb = f2bf_rne(a[i]);
        uh.u[i] = hb;
        ul.u[i] = f2bf_rne(a[i] - bf2f(hb));
    }
    const size_t base = ((size_t)(s * 16 + n) * 2) * 64 + lane;
    *(u16x8*)(wp + base * 8)        = uh.v;   // hi
    *(u16x8*)(wp + (base + 64) * 8) = ul.v;   // lo
}

// ---------------------------------------------------------------- main ----
// 640 threads = 10 waves: waves 0..7 = consumers (MFMA), waves 8..9 = producers
// (H load + f32->bf16 hi/lo cvt + LDS stage). Consumer wave w owns 4 M-tiles x
// 2 N-tiles (2w, 2w+1). One barrier per 64-k iter, double-buffered A.
__global__ __launch_bounds__(640, 2) void router_main(
    const float* __restrict__ H,
    const float* __restrict__ bias,
    const unsigned short* __restrict__ wp,
    float* __restrict__ out,
    int* __restrict__ ws)
{
    // union: Ahl dbuf (32 KiB) / Sc (65792 B)
    __shared__ __align__(16) char smraw[BM * SC_STRIDE * 4];
    __shared__ float biasS[NEXP];

    typedef unsigned short AhlBuf[2][2][4][64][8];   // [sub][h][m][lane][i]
    AhlBuf* Ahl = reinterpret_cast<AhlBuf*>(smraw);  // Ahl[buf]
    float*  Sc  = reinterpret_cast<float*>(smraw);

    const int tid  = threadIdx.x;
    const int lane = tid & 63;
    const int w    = tid >> 6;           // wave 0..9
    const int t0   = blockIdx.x * BM;
    const bool isCons = (tid < NCONS);

    if (tid < NEXP) biasS[tid] = bias[tid];

    f32x4 acc[4][2];   // [m][jj], expert tile = 2w+jj   (consumers only)
    #pragma unroll
    for (int m = 0; m < 4; ++m)
        #pragma unroll
        for (int jj = 0; jj < 2; ++jj)
            acc[m][jj] = (f32x4){0.f, 0.f, 0.f, 0.f};

    // ---- producer mapping (tid 512..639) ----
    // pw = producer wave (0/1) = sub; lane l: r = l&15, kq = l>>4; q = m (0..3)
    // t = t0 + 16*q + r ; k = 64*it + 32*pw + 8*kq + i
    const int ptid = tid - NCONS;
    const int pw   = (ptid >> 6) & 1;
    const int pr   = lane & 15;
    const int pkq  = lane >> 4;
    const float* Pbase = H + (size_t)(t0 + pr) * DIM + 32 * pw + 8 * pkq;

    float4 hp[4][2];   // prefetched H regs: [q][2 float4]

    auto loadH = [&](int it) {
        #pragma unroll
        for (int q = 0; q < 4; ++q) {
            const float* p = Pbase + (size_t)(16 * q) * DIM + 64 * it;
            hp[q][0] = *(const float4*)p;
            hp[q][1] = *(const float4*)(p + 4);
        }
    };
    auto stageIter = [&](int b) {
        #pragma unroll
        for (int q = 0; q < 4; ++q) {
            const float a[8] = {hp[q][0].x, hp[q][0].y, hp[q][0].z, hp[q][0].w,
                                hp[q][1].x, hp[q][1].y, hp[q][1].z, hp[q][1].w};
            union { unsigned short u[8]; u16x8 v; } uh, ul;
            #pragma unroll
            for (int i = 0; i < 8; ++i) {
                const unsigned short hb = f2bf_rne(a[i]);
                uh.u[i] = hb;
                ul.u[i] = f2bf_rne(a[i] - bf2f(hb));
            }
            *(u16x8*)&Ahl[b][pw][0][q][lane][0] = uh.v;   // lane-linear: conflict-free
            *(u16x8*)&Ahl[b][pw][1][q][lane][0] = ul.v;
        }
    };

    // ---- consumer helpers ----
    auto loadB = [&](int s, bf16x8 (&Bh)[2], bf16x8 (&Bl)[2]) {
        #pragma unroll
        for (int jj = 0; jj < 2; ++jj) {
            const size_t slot = ((size_t)(s * 16 + 2 * w + jj) * 2) * 64 + lane;
            Bh[jj] = *(const bf16x8*)(wp + slot * 8);
            Bl[jj] = *(const bf16x8*)(wp + (slot + 64) * 8);
        }
    };
    auto computeSub = [&](int b, int ss, bf16x8 (&Bh)[2], bf16x8 (&Bl)[2]) {
        bf16x8 Ah[4], Al[4];
        #pragma unroll
        for (int m = 0; m < 4; ++m) {
            Ah[m] = *(const bf16x8*)&Ahl[b][ss][0][m][lane][0];
            Al[m] = *(const bf16x8*)&Ahl[b][ss][1][m][lane][0];
        }
        __builtin_amdgcn_s_setprio(1);
        #pragma unroll
        for (int m = 0; m < 4; ++m)
            #pragma unroll
            for (int jj = 0; jj < 2; ++jj) {
                acc[m][jj] = __builtin_amdgcn_mfma_f32_16x16x32_bf16(Al[m], Bh[jj], acc[m][jj], 0, 0, 0);
                acc[m][jj] = __builtin_amdgcn_mfma_f32_16x16x32_bf16(Ah[m], Bl[jj], acc[m][jj], 0, 0, 0);
                acc[m][jj] = __builtin_amdgcn_mfma_f32_16x16x32_bf16(Ah[m], Bh[jj], acc[m][jj], 0, 0, 0);
            }
        __builtin_amdgcn_s_setprio(0);
    };

    bf16x8 Ba_h[2], Ba_l[2], Bb_h[2], Bb_l[2];

    // ---- prologue ----
    if (!isCons) {
        loadH(0);
        stageIter(0);        // buf0 = iter 0
        loadH(1);            // regs = iter 1
    } else {
        loadB(0, Ba_h, Ba_l);
    }
    __syncthreads();

    for (int it = 0; it < NIT; ++it) {
        const int cur = it & 1;
        if (isCons) {
            loadB(2 * it + 1, Bb_h, Bb_l);
            computeSub(cur, 0, Ba_h, Ba_l);
            loadB(min(2 * it + 2, 2 * NIT - 1), Ba_h, Ba_l);
            computeSub(cur, 1, Bb_h, Bb_l);
        } else {
            if (it + 1 < NIT) stageIter(cur ^ 1);   // stage iter+1 from regs
            if (it + 2 < NIT) loadH(it + 2);        // prefetch iter+2
        }
        __syncthreads();
    }

    // ---- epilogue: biased sigmoid -> Sc (consumers only) ----
    if (isCons) {
        const int rbase = (lane >> 4) * 4;
        const int cc    = lane & 15;
        #pragma unroll
        for (int m = 0; m < 4; ++m)
            #pragma unroll
            for (int jj = 0; jj < 2; ++jj)
                #pragma unroll
                for (int r = 0; r < 4; ++r) {
                    const int token  = 16 * m + rbase + r;
                    const int expert = 16 * (2 * w + jj) + cc;
                    const float sg = 1.0f / (1.0f + expf(-acc[m][jj][r]));
                    Sc[token * SC_STRIDE + expert] = sg + biasS[expert];
                }
    }
    __syncthreads();

    // ---- routing (fp32) + margin check (round-4..7 proven) ----
    if (tid < BM) {
        float* row = &Sc[tid * SC_STRIDE];

        float gs[NGROUP];
        for (int g = 0; g < NGROUP; ++g) {
            const int base = g * GSIZE;
            float m1 = -3e38f, m2 = -3e38f;
            for (int j = 0; j < GSIZE; ++j) {
                const float v = row[base + j];
                if (v > m1) { m2 = m1; m1 = v; }
                else if (v > m2) { m2 = v; }
            }
            gs[g] = m1 + m2;
        }

        unsigned gsel = 0;
        float minSel = 3e38f, maxUn = -3e38f;
        #pragma unroll
        for (int g = 0; g < NGROUP; ++g) {
            int rank = 0;
            #pragma unroll
            for (int h = 0; h < NGROUP; ++h)
                rank += (gs[h] > gs[g]) || (gs[h] == gs[g] && h < g);
            if (rank < TOPG) { gsel |= 1u << g; minSel = fminf(minSel, gs[g]); }
            else             { maxUn = fmaxf(maxUn, gs[g]); }
        }
        float minMargin = minSel - maxUn;

        float wk[TOPK];
        int   ik[TOPK];
        float wsum = 0.0f;
        float prev = 3e38f;
        #pragma unroll
        for (int k = 0; k < TOPK + 1; ++k) {
            float bv = -3e38f;
            int   bi = 0;
            for (int g = 0; g < NGROUP; ++g) {
                if (!((gsel >> g) & 1u)) continue;
                const int base = g * GSIZE;
                for (int j = 0; j < GSIZE; ++j) {
                    const int e = base + j;
                    const float v = row[e];
                    if (v > bv) { bv = v; bi = e; }
                }
            }
            if (k > 0) minMargin = fminf(minMargin, prev - bv);
            prev = bv;
            if (k < TOPK) {
                const float wv = bv - biasS[bi];
                wk[k] = wv; ik[k] = bi; wsum += wv;
                row[bi] = -3e38f;
            }
        }

        const float norm = (float)SCALE / wsum;
        const size_t t = (size_t)(t0 + tid);
        float* oi = out + t * TOPK;
        float* ow = out + (size_t)T_TOKENS * TOPK + t * TOPK;
        #pragma unroll
        for (int k = 0; k < TOPK; ++k) {
            oi[k] = (float)ik[k];
            ow[k] = wk[k] * norm;
        }

        if (minMargin < TAU) {
            const int r = atomicAdd(ws, 1);
            ws[RLIST_OFF + r] = t0 + tid;
        }
    }
}

// -------------------------------------------------------------- rescue ----
// 2 tokens per block-iteration; threads = 64 experts x 4 k-chunks; exact fp64.
__global__ __launch_bounds__(256) void router_rescue(
    const float* __restrict__ H,
    const float* __restrict__ Wt,
    const float* __restrict__ bias,
    float* __restrict__ out,
    const int* __restrict__ ws)
{
    __shared__ float  Hs[2][DIM];          // 16 KiB
    __shared__ double Part[4][2][NEXP];    // 16 KiB
    __shared__ double Sd[2][NEXP];         //  4 KiB

    const int tid = threadIdx.x;
    const int nR  = ws[0];
    const int e0  = tid & 63;
    const int kc  = tid >> 6;              // 0..3

    for (int base = blockIdx.x * 2; base < nR; base += gridDim.x * 2) {
        const int nt = min(2, nR - base);
        __syncthreads();

        for (int j = 0; j < nt; ++j) {
            const int t = ws[RLIST_OFF + base + j];
            const float* hp = H + (size_t)t * DIM + tid * 8;
            const float4 a = *(const float4*)hp;
            const float4 b = *(const float4*)(hp + 4);
            float* d = &Hs[j][tid * 8];
            d[0] = a.x; d[1] = a.y; d[2] = a.z; d[3] = a.w;
            d[4] = b.x; d[5] = b.y; d[6] = b.z; d[7] = b.w;
        }
        __syncthreads();

        #pragma unroll
        for (int q = 0; q < 4; ++q) {
            const int e = e0 + 64 * q;
            const float* wr  = Wt + (size_t)e * DIM + kc * 512;
            const float* h0p = &Hs[0][kc * 512];
            const float* h1p = &Hs[1][kc * 512];
            double a00 = 0.0, a01 = 0.0, a10 = 0.0, a11 = 0.0;   // 4 indep chains
            for (int k = 0; k < 512; k += 8) {
                const float4 w0 = *(const float4*)(wr + k);
                const float4 w1 = *(const float4*)(wr + k + 4);
                a00 = fma((double)h0p[k + 0], (double)w0.x, a00);
                a00 = fma((double)h0p[k + 1], (double)w0.y, a00);
                a00 = fma((double)h0p[k + 2], (double)w0.z, a00);
                a00 = fma((double)h0p[k + 3], (double)w0.w, a00);
                a01 = fma((double)h0p[k + 4], (double)w1.x, a01);
                a01 = fma((double)h0p[k + 5], (double)w1.y, a01);
                a01 = fma((double)h0p[k + 6], (double)w1.z, a01);
                a01 = fma((double)h0p[k + 7], (double)w1.w, a01);
                a10 = fma((double)h1p[k + 0], (double)w0.x, a10);
                a10 = fma((double)h1p[k + 1], (double)w0.y, a10);
                a10 = fma((double)h1p[k + 2], (double)w0.z, a10);
                a10 = fma((double)h1p[k + 3], (double)w0.w, a10);
                a11 = fma((double)h1p[k + 4], (double)w1.x, a11);
                a11 = fma((double)h1p[k + 5], (double)w1.y, a11);
                a11 = fma((double)h1p[k + 6], (double)w1.z, a11);
                a11 = fma((double)h1p[k + 7], (double)w1.w, a11);
            }
            Part[kc][0][e] = a00 + a01;
            Part[kc][1][e] = a10 + a11;
        }
        __syncthreads();

        {   // reduce chunks (fixed order) + fp64 sigmoid + bias
            #pragma unroll
            for (int j = 0; j < 2; ++j) {
                const double sum = ((Part[0][j][tid] + Part[1][j][tid]) + Part[2][j][tid]) + Part[3][j][tid];
                Sd[j][tid] = 1.0 / (1.0 + exp(-sum)) + (double)bias[tid];
            }
        }
        __syncthreads();

        if (tid < nt) {
            double* row = Sd[tid];

            double gs[NGROUP];
            for (int g = 0; g < NGROUP; ++g) {
                const int b0 = g * GSIZE;
                double m1 = -1e300, m2 = -1e300;
                for (int j = 0; j < GSIZE; ++j) {
                    const double v = row[b0 + j];
                    if (v > m1) { m2 = m1; m1 = v; }
                    else if (v > m2) { m2 = v; }
                }
                gs[g] = m1 + m2;
            }

            unsigned gsel = 0;
            for (int g = 0; g < NGROUP; ++g) {
                int rank = 0;
                for (int h = 0; h < NGROUP; ++h)
                    rank += (gs[h] > gs[g]) || (gs[h] == gs[g] && h < g);
                if (rank < TOPG) gsel |= 1u << g;
            }

            double wk[TOPK];
            int    ik[TOPK];
            double wsum = 0.0;
            for (int k = 0; k < TOPK; ++k) {
                double bv = -1e300;
                int    bi = 0;
                for (int g = 0; g < NGROUP; ++g) {
                    if (!((gsel >> g) & 1u)) continue;
                    const int b0 = g * GSIZE;
                    for (int j = 0; j < GSIZE; ++j) {
                        const int e = b0 + j;
                        if (row[e] > bv) { bv = row[e]; bi = e; }
                    }
                }
                const double wv = bv - (double)bias[bi];
                wk[k] = wv; ik[k] = bi; wsum += wv;
                row[bi] = -1e300;
            }

            const double norm = SCALE / wsum;
            const int t = ws[RLIST_OFF + base + tid];
            float* oi = out + (size_t)t * TOPK;
            float* ow = out + (size_t)T_TOKENS * TOPK + (size_t)t * TOPK;
            for (int k = 0; k < TOPK; ++k) {
                oi[k] = (float)ik[k];
                ow[k] = (float)(wk[k] * norm);
            }
        }
    }
}

extern "C" void kernel_launch(void* const* d_in, const int* in_sizes, int n_in,
                              void* d_out, int out_size, void* d_ws, size_t ws_size,
                              hipStream_t stream) {
    const float* H    = (const float*)d_in[0];
    const float* Wt   = (const float*)d_in[1];
    const float* bias = (const float*)d_in[2];
    float* out = (float*)d_out;
    int*   ws  = (int*)d_ws;
    unsigned short* wp = (unsigned short*)((char*)d_ws + WPACK_OFF_BYTES);

    pack_w_kernel<<<256, 256, 0, stream>>>(Wt, wp, ws);
    router_main<<<T_TOKENS / BM, 640, 0, stream>>>(H, bias, wp, out, ws);
    router_rescue<<<512, 256, 0, stream>>>(H, Wt, bias, out, ws);
}